// Round 26
// baseline (56.734 us; speedup 1.0000x reference)
//
#include <hip/hip_runtime.h>
#include <hip/hip_bf16.h>
#include <math.h>

typedef __attribute__((ext_vector_type(8))) short short8;
typedef __attribute__((ext_vector_type(4))) float f32x4;

#define SS 2048
#define DD 768
#define HDIM 64
#define MM 16384   // total rows = 8*2048

// round-to-nearest-even fp32 -> bf16 bits (proven R0-R5)
__device__ __forceinline__ short f2bf(float f) {
    union { float f; unsigned u; } v; v.f = f;
    unsigned r = (v.u + 0x7fffu + ((v.u >> 16) & 1u)) >> 16;
    return (short)r;
}
__device__ __forceinline__ float bf2f(short s) {
    union { float f; unsigned u; } v;
    v.u = ((unsigned)(unsigned short)s) << 16;
    return v.f;
}

// async global->LDS, 16B per lane; LDS dest = wave-uniform base (+lane*16 by HW),
// global src is per-lane (pre-swizzled for bank-conflict-free ds_read).
__device__ __forceinline__ void gl_lds(const void* g, void* l) {
    __builtin_amdgcn_global_load_lds(
        (const __attribute__((address_space(1))) unsigned*)g,
        (__attribute__((address_space(3))) unsigned*)l, 16, 0, 0);
}

// ---------------- kernel 1: W -> Wt bf16 transpose, coalesced via LDS tile.
// Block = (matrix m, k-tile of 64). 36 blocks x 256 thr.
__global__ __launch_bounds__(256)
void prep_w(const float* __restrict__ Wq, const float* __restrict__ Wk,
            const float* __restrict__ Wv, short* __restrict__ Wt) {
    __shared__ short lds[64 * 72];   // [c][k], pad 72 (16B-aligned rows)
    const int m  = blockIdx.x / 12;
    const int kt = blockIdx.x % 12;
    const float* W = (m == 0) ? Wq : (m == 1) ? Wk : Wv;
    const int tid = threadIdx.x;
    const int c = tid & 63, kr = tid >> 6;     // c: col, kr: k-phase row

    #pragma unroll
    for (int p = 0; p < 16; p++) {
        int k = p * 4 + kr;                    // 0..63
        lds[c * 72 + k] = f2bf(W[(size_t)(kt * 64 + k) * HDIM + c]);
    }
    __syncthreads();

    const int col = tid >> 2, j0 = (tid & 3) * 16;
    short* dst = Wt + (size_t)(m * 64 + col) * DD + kt * 64 + j0;
    *(short8*)(dst)     = *(const short8*)&lds[col * 72 + j0];
    *(short8*)(dst + 8) = *(const short8*)&lds[col * 72 + j0 + 8];
}

// ---------------- kernel 2: QKV projection, staged GEMM (R9 exact, frozen).
// 512 blocks x 8 waves; tile 32 rows x 192 cols; BK=64 double-buffered.
__global__ __launch_bounds__(512)
void proj_qkv(const float* __restrict__ X, const short* __restrict__ Wt,
              const float* __restrict__ bq, const float* __restrict__ bk,
              const float* __restrict__ bv,
              short* __restrict__ Qg, short* __restrict__ Kg, short* __restrict__ Vt) {
    __shared__ float Xl[2][2048];    // 8 KB/buf: [32 rows][64 k] fp32, swizzled
    __shared__ short Wl[2][12288];   // 24 KB/buf: [192 cols][64 k] bf16, swizzled
    const int tid = threadIdx.x;
    const int w = tid >> 6, lane = tid & 63;
    const int lr = lane & 15, lg = lane >> 4;
    const int wr = w >> 2, wc = w & 3;           // wave = 16 rows x 48 cols
    const int row0 = blockIdx.x * 32;

    f32x4 acc[3];
    #pragma unroll
    for (int cf = 0; cf < 3; cf++) acc[cf] = (f32x4)0.0f;

    auto stage = [&](int kk, int buf) {
        {   // X slice: 8 insts total, one per wave
            int o = w * 1024 + lane * 16;
            int row = o >> 8, ch = (o >> 4) & 15;
            const char* src = (const char*)X + (size_t)(row0 + row) * 3072
                              + kk * 256 + ((ch ^ (row & 7)) << 4);
            gl_lds(src, (char*)&Xl[buf][0] + w * 1024);
        }
        #pragma unroll
        for (int s = 0; s < 3; s++) {   // W slice: 24 insts, 3 per wave
            int i = w * 3 + s;
            int o = i * 1024 + lane * 16;
            int col = o >> 7, ch = (o >> 4) & 7;
            const char* src = (const char*)Wt + (size_t)col * 1536
                              + kk * 128 + ((ch ^ (col & 7)) << 4);
            gl_lds(src, (char*)&Wl[buf][0] + i * 1024);
        }
    };

    stage(0, 0);
    __syncthreads();
    int buf = 0;
    for (int kk = 0; kk < 12; kk++) {
        if (kk < 11) stage(kk + 1, buf ^ 1);
        const char* xb = (const char*)&Xl[buf][0];
        const char* wb = (const char*)&Wl[buf][0];
        #pragma unroll
        for (int ksub = 0; ksub < 2; ksub++) {
            int r = wr * 16 + lr;
            int b0 = r * 256 + ksub * 128 + lg * 32;
            f32x4 x0 = *(const f32x4*)(xb + ((b0)      ^ ((r & 7) << 4)));
            f32x4 x1 = *(const f32x4*)(xb + ((b0 + 16) ^ ((r & 7) << 4)));
            short8 a;
            a[0]=f2bf(x0[0]); a[1]=f2bf(x0[1]); a[2]=f2bf(x0[2]); a[3]=f2bf(x0[3]);
            a[4]=f2bf(x1[0]); a[5]=f2bf(x1[1]); a[6]=f2bf(x1[2]); a[7]=f2bf(x1[3]);
            #pragma unroll
            for (int cf = 0; cf < 3; cf++) {
                int col = wc * 48 + cf * 16 + lr;
                short8 bfr = *(const short8*)(wb +
                    ((col * 128 + ksub * 64 + lg * 16) ^ ((col & 7) << 4)));
                acc[cf] = __builtin_amdgcn_mfma_f32_16x16x32_bf16(a, bfr, acc[cf], 0, 0, 0);
            }
        }
        __syncthreads();
        buf ^= 1;
    }

    #pragma unroll
    for (int cf = 0; cf < 3; cf++) {
        int gcol = wc * 48 + cf * 16 + lr;
        int m = gcol >> 6, cc = gcol & 63;
        float bias = (m == 0 ? bq : m == 1 ? bk : bv)[cc];
        #pragma unroll
        for (int i = 0; i < 4; i++) {
            int r = row0 + wr * 16 + lg * 4 + i;
            short o = f2bf(acc[cf][i] + bias);
            if (m == 0)      Qg[(size_t)r * HDIM + cc] = o;
            else if (m == 1) Kg[(size_t)r * HDIM + cc] = o;
            else             Vt[(size_t)cc * MM + r]   = o;
        }
    }
}

// ---------------- kernel 3: flash attention phase A (R14 body; C=2; XCD-pinned).
// 1D grid 1088 = 136 chunks x 8 batches; id%8 = batch -> XCD.
// Block = (b, 128-row q-tile J, kv chunk of <=2 64-row tiles).
__global__ __launch_bounds__(512)
void attn_part(const short* __restrict__ Qg, const short* __restrict__ Kg,
               const short* __restrict__ Vt,
               short* __restrict__ Opart, float* __restrict__ Ml,
               float* __restrict__ out) {
    __shared__ short Kl[2][4096];   // 8 KB/buf: [64 kv][64 d], swizzled
    __shared__ short Vl[2][4096];   // 8 KB/buf: [64 d][64 kv], swizzled
    __shared__ short Pl[8][1024];   // 2 KB per wave, swizzled
    const int tid = threadIdx.x;
    const int w = tid >> 6, lane = tid & 63;
    const int lr = lane & 15, lg = lane >> 4;
    const int b = (int)blockIdx.x & 7;           // XCD pin: id%8 = batch
    const int cidx = (int)blockIdx.x >> 3;       // 0..135, low = heavy

    // decode: r0 = 135-cidx (lightest-first rank); J has J+1 chunks
    int r0 = 135 - cidx;
    int J = 0, acc0 = 0;
    while (r0 >= acc0 + (J + 1)) { acc0 += (J + 1); J++; }
    const int c = r0 - acc0;
    const int t0 = 2 * c;
    const int t1 = min(2 * J + 2, 2 * c + 2);

    const int q0 = J * 128 + w * 16;
    char* plbase = (char*)&Pl[w][0];

    short8 qf[2];
    qf[0] = *(const short8*)(Qg + ((size_t)b * SS + q0 + lr) * HDIM + lg * 8);
    qf[1] = *(const short8*)(Qg + ((size_t)b * SS + q0 + lr) * HDIM + 32 + lg * 8);

    f32x4 oacc[4];
    #pragma unroll
    for (int d = 0; d < 4; d++) oacc[d] = (f32x4)0.0f;
    float mrow[4] = {-INFINITY, -INFINITY, -INFINITY, -INFINITY};
    float lrow[4] = {0.f, 0.f, 0.f, 0.f};
    const float scl = 0.03608439182435161f;   // 1/sqrt(768)

    auto stage = [&](int t, int buf) {
        const int kv0 = t * 64;
        {   // K tile
            int o = w * 1024 + lane * 16;
            int row = o >> 7, ch = (o >> 4) & 7;
            const char* src = (const char*)Kg + ((size_t)b * SS + kv0) * 128
                              + row * 128 + ((ch ^ (row & 7)) << 4);
            gl_lds(src, (char*)&Kl[buf][0] + w * 1024);
        }
        {   // V tile
            int o = w * 1024 + lane * 16;
            int col = o >> 7, ch = (o >> 4) & 7;
            const char* src = (const char*)Vt + (size_t)col * (MM * 2)
                              + ((size_t)b * SS + kv0) * 2 + ((ch ^ (col & 7)) << 4);
            gl_lds(src, (char*)&Vl[buf][0] + w * 1024);
        }
    };

    stage(t0, 0);
    __syncthreads();
    int buf = 0;
    for (int t = t0; t < t1; t++) {
        if (t + 1 < t1) stage(t + 1, buf ^ 1);
        const int kv0 = t * 64;
        const bool active = (kv0 <= q0 + 15);
        if (active) {
            const char* kb = (const char*)&Kl[buf][0];
            f32x4 sacc[4];
            #pragma unroll
            for (int ct = 0; ct < 4; ct++) sacc[ct] = (f32x4)0.0f;
            #pragma unroll
            for (int ct = 0; ct < 4; ct++) {
                int row = ct * 16 + lr;
                short8 k0 = *(const short8*)(kb + ((row * 128 +      lg * 16) ^ ((row & 7) << 4)));
                short8 k1 = *(const short8*)(kb + ((row * 128 + 64 + lg * 16) ^ ((row & 7) << 4)));
                sacc[ct] = __builtin_amdgcn_mfma_f32_16x16x32_bf16(qf[0], k0, sacc[ct], 0, 0, 0);
                sacc[ct] = __builtin_amdgcn_mfma_f32_16x16x32_bf16(qf[1], k1, sacc[ct], 0, 0, 0);
            }

            const bool maskt = (kv0 + 63 > q0);
            float p[4][4];
            float rm[4] = {-1e30f, -1e30f, -1e30f, -1e30f};
            #pragma unroll
            for (int ct = 0; ct < 4; ct++) {
                #pragma unroll
                for (int i = 0; i < 4; i++) {
                    float s = sacc[ct][i] * scl;
                    if (maskt) {
                        int kv = kv0 + ct * 16 + lr;
                        int qr = q0 + lg * 4 + i;
                        if (kv > qr) s = -1e30f;
                    }
                    p[ct][i] = s;
                    rm[i] = fmaxf(rm[i], s);
                }
            }
            #pragma unroll
            for (int i = 0; i < 4; i++) {
                float v = rm[i];
                v = fmaxf(v, __shfl_xor(v, 1));
                v = fmaxf(v, __shfl_xor(v, 2));
                v = fmaxf(v, __shfl_xor(v, 4));
                v = fmaxf(v, __shfl_xor(v, 8));
                rm[i] = v;
            }
            if (t == t0) {
                // first active tile: mrow=-inf, lrow=0, oacc=0 -> direct init,
                // skip the rescale (all its products are zero).
                #pragma unroll
                for (int i = 0; i < 4; i++) mrow[i] = rm[i];
            } else {
                #pragma unroll
                for (int i = 0; i < 4; i++) {
                    float mn = fmaxf(mrow[i], rm[i]);
                    float scale = __expf(mrow[i] - mn);
                    mrow[i] = mn;
                    lrow[i] *= scale;
                    for (int d = 0; d < 4; d++) oacc[d][i] *= scale;
                }
            }
            float rs[4];
            #pragma unroll
            for (int i = 0; i < 4; i++) {
                float sum = 0.f;
                #pragma unroll
                for (int ct = 0; ct < 4; ct++) {
                    float e = __expf(p[ct][i] - mrow[i]);
                    p[ct][i] = e;
                    sum += e;
                }
                rs[i] = sum;
            }
            #pragma unroll
            for (int i = 0; i < 4; i++) {
                float v = rs[i];
                v += __shfl_xor(v, 1);
                v += __shfl_xor(v, 2);
                v += __shfl_xor(v, 4);
                v += __shfl_xor(v, 8);
                lrow[i] += v;
            }

            // P (C-layout) -> per-wave LDS bf16, XOR-swizzled
            #pragma unroll
            for (int ct = 0; ct < 4; ct++) {
                #pragma unroll
                for (int i = 0; i < 4; i++) {
                    int r = lg * 4 + i;
                    int byteoff = r * 128 + (ct * 16 + lr) * 2;
                    *(short*)(plbase + (byteoff ^ ((r & 7) << 4))) = f2bf(p[ct][i]);
                }
            }

            const char* vb = (const char*)&Vl[buf][0];
            #pragma unroll
            for (int ks = 0; ks < 2; ks++) {
                int byteoff = lr * 128 + ks * 64 + lg * 16;
                short8 pf = *(const short8*)(plbase + (byteoff ^ ((lr & 7) << 4)));
                #pragma unroll
                for (int d = 0; d < 4; d++) {
                    int col = d * 16 + lr;
                    short8 vf = *(const short8*)(vb +
                        ((col * 128 + ks * 64 + lg * 16) ^ ((col & 7) << 4)));
                    oacc[d] = __builtin_amdgcn_mfma_f32_16x16x32_bf16(pf, vf, oacc[d], 0, 0, 0);
                }
            }
        }
        __syncthreads();
        buf ^= 1;
    }

    if (J == 0) {
        // single chunk: write normalized output directly
        #pragma unroll
        for (int d = 0; d < 4; d++)
            #pragma unroll
            for (int i = 0; i < 4; i++)
                out[((size_t)b * SS + q0 + lg * 4 + i) * HDIM + d * 16 + lr]
                    = oacc[d][i] / lrow[i];
    } else {
        const int pb = (b * 16 + J) * 16 + c;
        short* op = Opart + (size_t)pb * 8192 + (size_t)(w * 16) * 64;
        #pragma unroll
        for (int d = 0; d < 4; d++)
            #pragma unroll
            for (int i = 0; i < 4; i++)
                op[(lg * 4 + i) * 64 + d * 16 + lr] = f2bf(oacc[d][i]);
        if (lr == 0) {
            float* ml = Ml + (size_t)pb * 256;
            for (int i = 0; i < 4; i++) {
                ml[w * 16 + lg * 4 + i]       = mrow[i];
                ml[128 + w * 16 + lg * 4 + i] = lrow[i];
            }
        }
    }
}

// ---------------- kernel 4: combine bf16 partials -> out (J = 1..15).
// 1D grid 240 (2 row-halves per J-tile); id%8 = batch -> producers' XCD.
__global__ __launch_bounds__(256)
void attn_comb(const short* __restrict__ Opart, const float* __restrict__ Ml,
               float* __restrict__ out) {
    const int b = (int)blockIdx.x & 7;
    const int t = (int)blockIdx.x >> 3;       // 0..29
    const int J = (t >> 1) + 1;
    const int rh = t & 1;                     // row half
    const int nc = J + 1;                     // chunks for this J (2..16)
    const int tid = threadIdx.x;
    const int r = rh * 64 + (tid >> 2);       // row 0..127
    const int cq = tid & 3;                   // col quarter (16 cols)
    const int base = (b * 16 + J) * 16;

    float m = -INFINITY;
    for (int c = 0; c < nc; c++) m = fmaxf(m, Ml[(size_t)(base + c) * 256 + r]);

    float L = 0.f;
    f32x4 acc[4];
    #pragma unroll
    for (int q = 0; q < 4; q++) acc[q] = (f32x4)0.0f;
    for (int c = 0; c < nc; c++) {
        const float* ml = Ml + (size_t)(base + c) * 256;
        float sc = __expf(ml[r] - m);
        L += ml[128 + r] * sc;
        const short* op = Opart + (size_t)(base + c) * 8192 + r * 64 + cq * 16;
        #pragma unroll
        for (int q = 0; q < 2; q++) {
            short8 s = *(const short8*)(op + q * 8);
            f32x4 lo = {bf2f(s[0]), bf2f(s[1]), bf2f(s[2]), bf2f(s[3])};
            f32x4 hi = {bf2f(s[4]), bf2f(s[5]), bf2f(s[6]), bf2f(s[7])};
            acc[q * 2]     += lo * sc;
            acc[q * 2 + 1] += hi * sc;
        }
    }
    float inv = 1.0f / L;
    float* o = out + ((size_t)b * SS + J * 128 + r) * HDIM + cq * 16;
    #pragma unroll
    for (int q = 0; q < 4; q++) {
        f32x4 v = acc[q] * inv;
        *(f32x4*)(o + q * 4) = v;
    }
}

extern "C" void kernel_launch(void* const* d_in, const int* in_sizes, int n_in,
                              void* d_out, int out_size, void* d_ws, size_t ws_size,
                              hipStream_t stream) {
    const float* X  = (const float*)d_in[0];
    const float* Wq = (const float*)d_in[1];
    const float* bq = (const float*)d_in[2];
    const float* Wk = (const float*)d_in[3];
    const float* bk = (const float*)d_in[4];
    const float* Wv = (const float*)d_in[5];
    const float* bv = (const float*)d_in[6];
    float* out = (float*)d_out;

    char* ws = (char*)d_ws;
    short* Wt = (short*)(ws);                               // 294912 B
    short* Qg = (short*)(ws + 294912);                      // 2 MB
    short* Kg = (short*)(ws + 294912 + 2097152);            // 2 MB
    short* Vt = (short*)(ws + 294912 + 2 * 2097152);        // 2 MB
    size_t opOff = 294912 + 3 * (size_t)2097152;
    short* Op = (short*)(ws + opOff);                       // 2048*8192*2 = 33.6 MB
    float* Ml = (float*)(ws + opOff + (size_t)2048 * 8192 * 2);  // 2 MB

    prep_w<<<36, 256, 0, stream>>>(Wq, Wk, Wv, Wt);
    proj_qkv<<<512, 512, 0, stream>>>(X, Wt, bq, bk, bv, Qg, Kg, Vt);
    attn_part<<<1088, 512, 0, stream>>>(Qg, Kg, Vt, Op, Ml, out);
    attn_comb<<<240, 256, 0, stream>>>(Op, Ml, out);
}

// Round 27
// 54.302 us; speedup vs baseline: 1.0448x; 1.0448x over previous
//
#include <hip/hip_runtime.h>
#include <hip/hip_bf16.h>
#include <math.h>

typedef __attribute__((ext_vector_type(8))) short short8;
typedef __attribute__((ext_vector_type(4))) float f32x4;

#define SS 2048
#define DD 768
#define HDIM 64
#define MM 16384   // total rows = 8*2048

// round-to-nearest-even fp32 -> bf16 bits (proven R0-R5)
__device__ __forceinline__ short f2bf(float f) {
    union { float f; unsigned u; } v; v.f = f;
    unsigned r = (v.u + 0x7fffu + ((v.u >> 16) & 1u)) >> 16;
    return (short)r;
}
__device__ __forceinline__ float bf2f(short s) {
    union { float f; unsigned u; } v;
    v.u = ((unsigned)(unsigned short)s) << 16;
    return v.f;
}

// async global->LDS, 16B per lane; LDS dest = wave-uniform base (+lane*16 by HW),
// global src is per-lane (pre-swizzled for bank-conflict-free ds_read).
__device__ __forceinline__ void gl_lds(const void* g, void* l) {
    __builtin_amdgcn_global_load_lds(
        (const __attribute__((address_space(1))) unsigned*)g,
        (__attribute__((address_space(3))) unsigned*)l, 16, 0, 0);
}

// ---------------- kernel 1: W -> Wt bf16 transpose, coalesced via LDS tile.
// Block = (matrix m, k-tile of 64). 36 blocks x 256 thr.
__global__ __launch_bounds__(256)
void prep_w(const float* __restrict__ Wq, const float* __restrict__ Wk,
            const float* __restrict__ Wv, short* __restrict__ Wt) {
    __shared__ short lds[64 * 72];   // [c][k], pad 72 (16B-aligned rows)
    const int m  = blockIdx.x / 12;
    const int kt = blockIdx.x % 12;
    const float* W = (m == 0) ? Wq : (m == 1) ? Wk : Wv;
    const int tid = threadIdx.x;
    const int c = tid & 63, kr = tid >> 6;     // c: col, kr: k-phase row

    #pragma unroll
    for (int p = 0; p < 16; p++) {
        int k = p * 4 + kr;                    // 0..63
        lds[c * 72 + k] = f2bf(W[(size_t)(kt * 64 + k) * HDIM + c]);
    }
    __syncthreads();

    const int col = tid >> 2, j0 = (tid & 3) * 16;
    short* dst = Wt + (size_t)(m * 64 + col) * DD + kt * 64 + j0;
    *(short8*)(dst)     = *(const short8*)&lds[col * 72 + j0];
    *(short8*)(dst + 8) = *(const short8*)&lds[col * 72 + j0 + 8];
}

// ---------------- kernel 2: QKV projection, staged GEMM (R9 exact, frozen).
// 512 blocks x 8 waves; tile 32 rows x 192 cols; BK=64 double-buffered.
__global__ __launch_bounds__(512)
void proj_qkv(const float* __restrict__ X, const short* __restrict__ Wt,
              const float* __restrict__ bq, const float* __restrict__ bk,
              const float* __restrict__ bv,
              short* __restrict__ Qg, short* __restrict__ Kg, short* __restrict__ Vt) {
    __shared__ float Xl[2][2048];    // 8 KB/buf: [32 rows][64 k] fp32, swizzled
    __shared__ short Wl[2][12288];   // 24 KB/buf: [192 cols][64 k] bf16, swizzled
    const int tid = threadIdx.x;
    const int w = tid >> 6, lane = tid & 63;
    const int lr = lane & 15, lg = lane >> 4;
    const int wr = w >> 2, wc = w & 3;           // wave = 16 rows x 48 cols
    const int row0 = blockIdx.x * 32;

    f32x4 acc[3];
    #pragma unroll
    for (int cf = 0; cf < 3; cf++) acc[cf] = (f32x4)0.0f;

    auto stage = [&](int kk, int buf) {
        {   // X slice: 8 insts total, one per wave
            int o = w * 1024 + lane * 16;
            int row = o >> 8, ch = (o >> 4) & 15;
            const char* src = (const char*)X + (size_t)(row0 + row) * 3072
                              + kk * 256 + ((ch ^ (row & 7)) << 4);
            gl_lds(src, (char*)&Xl[buf][0] + w * 1024);
        }
        #pragma unroll
        for (int s = 0; s < 3; s++) {   // W slice: 24 insts, 3 per wave
            int i = w * 3 + s;
            int o = i * 1024 + lane * 16;
            int col = o >> 7, ch = (o >> 4) & 7;
            const char* src = (const char*)Wt + (size_t)col * 1536
                              + kk * 128 + ((ch ^ (col & 7)) << 4);
            gl_lds(src, (char*)&Wl[buf][0] + i * 1024);
        }
    };

    stage(0, 0);
    __syncthreads();
    int buf = 0;
    for (int kk = 0; kk < 12; kk++) {
        if (kk < 11) stage(kk + 1, buf ^ 1);
        const char* xb = (const char*)&Xl[buf][0];
        const char* wb = (const char*)&Wl[buf][0];
        #pragma unroll
        for (int ksub = 0; ksub < 2; ksub++) {
            int r = wr * 16 + lr;
            int b0 = r * 256 + ksub * 128 + lg * 32;
            f32x4 x0 = *(const f32x4*)(xb + ((b0)      ^ ((r & 7) << 4)));
            f32x4 x1 = *(const f32x4*)(xb + ((b0 + 16) ^ ((r & 7) << 4)));
            short8 a;
            a[0]=f2bf(x0[0]); a[1]=f2bf(x0[1]); a[2]=f2bf(x0[2]); a[3]=f2bf(x0[3]);
            a[4]=f2bf(x1[0]); a[5]=f2bf(x1[1]); a[6]=f2bf(x1[2]); a[7]=f2bf(x1[3]);
            #pragma unroll
            for (int cf = 0; cf < 3; cf++) {
                int col = wc * 48 + cf * 16 + lr;
                short8 bfr = *(const short8*)(wb +
                    ((col * 128 + ksub * 64 + lg * 16) ^ ((col & 7) << 4)));
                acc[cf] = __builtin_amdgcn_mfma_f32_16x16x32_bf16(a, bfr, acc[cf], 0, 0, 0);
            }
        }
        __syncthreads();
        buf ^= 1;
    }

    #pragma unroll
    for (int cf = 0; cf < 3; cf++) {
        int gcol = wc * 48 + cf * 16 + lr;
        int m = gcol >> 6, cc = gcol & 63;
        float bias = (m == 0 ? bq : m == 1 ? bk : bv)[cc];
        #pragma unroll
        for (int i = 0; i < 4; i++) {
            int r = row0 + wr * 16 + lg * 4 + i;
            short o = f2bf(acc[cf][i] + bias);
            if (m == 0)      Qg[(size_t)r * HDIM + cc] = o;
            else if (m == 1) Kg[(size_t)r * HDIM + cc] = o;
            else             Vt[(size_t)cc * MM + r]   = o;
        }
    }
}

// ---------------- kernel 3: flash attention phase A (R14 geometry; C=3;
// XCD-pinned; first-tile rescale skip — t==t0 initializes mrow/lrow directly).
__global__ __launch_bounds__(512)
void attn_part(const short* __restrict__ Qg, const short* __restrict__ Kg,
               const short* __restrict__ Vt,
               short* __restrict__ Opart, float* __restrict__ Ml,
               float* __restrict__ out) {
    __shared__ short Kl[2][4096];   // 8 KB/buf: [64 kv][64 d], swizzled
    __shared__ short Vl[2][4096];   // 8 KB/buf: [64 d][64 kv], swizzled
    __shared__ short Pl[8][1024];   // 2 KB per wave, swizzled
    const int tid = threadIdx.x;
    const int w = tid >> 6, lane = tid & 63;
    const int lr = lane & 15, lg = lane >> 4;
    const int b = (int)blockIdx.x & 7;           // XCD pin: id%8 = batch
    const int cidx = (int)blockIdx.x >> 3;       // 0..95, low = heavy

    // decode: r = 95-cidx (lightest-first rank); J has nJ = (2J+4)/3 chunks
    int r0 = 95 - cidx;
    int J = 0, acc0 = 0;
    while (r0 >= acc0 + (2 * J + 4) / 3) { acc0 += (2 * J + 4) / 3; J++; }
    const int c = r0 - acc0;
    const int t0 = 3 * c;
    const int t1 = min(2 * J + 2, 3 * c + 3);

    const int q0 = J * 128 + w * 16;
    char* plbase = (char*)&Pl[w][0];

    short8 qf[2];
    qf[0] = *(const short8*)(Qg + ((size_t)b * SS + q0 + lr) * HDIM + lg * 8);
    qf[1] = *(const short8*)(Qg + ((size_t)b * SS + q0 + lr) * HDIM + 32 + lg * 8);

    f32x4 oacc[4];
    #pragma unroll
    for (int d = 0; d < 4; d++) oacc[d] = (f32x4)0.0f;
    float mrow[4] = {-INFINITY, -INFINITY, -INFINITY, -INFINITY};
    float lrow[4] = {0.f, 0.f, 0.f, 0.f};
    const float scl = 0.03608439182435161f;   // 1/sqrt(768)

    auto stage = [&](int t, int buf) {
        const int kv0 = t * 64;
        {   // K tile
            int o = w * 1024 + lane * 16;
            int row = o >> 7, ch = (o >> 4) & 7;
            const char* src = (const char*)Kg + ((size_t)b * SS + kv0) * 128
                              + row * 128 + ((ch ^ (row & 7)) << 4);
            gl_lds(src, (char*)&Kl[buf][0] + w * 1024);
        }
        {   // V tile
            int o = w * 1024 + lane * 16;
            int col = o >> 7, ch = (o >> 4) & 7;
            const char* src = (const char*)Vt + (size_t)col * (MM * 2)
                              + ((size_t)b * SS + kv0) * 2 + ((ch ^ (col & 7)) << 4);
            gl_lds(src, (char*)&Vl[buf][0] + w * 1024);
        }
    };

    stage(t0, 0);
    __syncthreads();
    int buf = 0;
    for (int t = t0; t < t1; t++) {
        if (t + 1 < t1) stage(t + 1, buf ^ 1);
        const int kv0 = t * 64;
        const bool active = (kv0 <= q0 + 15);
        if (active) {
            const char* kb = (const char*)&Kl[buf][0];
            f32x4 sacc[4];
            #pragma unroll
            for (int ct = 0; ct < 4; ct++) sacc[ct] = (f32x4)0.0f;
            #pragma unroll
            for (int ct = 0; ct < 4; ct++) {
                int row = ct * 16 + lr;
                short8 k0 = *(const short8*)(kb + ((row * 128 +      lg * 16) ^ ((row & 7) << 4)));
                short8 k1 = *(const short8*)(kb + ((row * 128 + 64 + lg * 16) ^ ((row & 7) << 4)));
                sacc[ct] = __builtin_amdgcn_mfma_f32_16x16x32_bf16(qf[0], k0, sacc[ct], 0, 0, 0);
                sacc[ct] = __builtin_amdgcn_mfma_f32_16x16x32_bf16(qf[1], k1, sacc[ct], 0, 0, 0);
            }

            const bool maskt = (kv0 + 63 > q0);
            float p[4][4];
            float rm[4] = {-1e30f, -1e30f, -1e30f, -1e30f};
            #pragma unroll
            for (int ct = 0; ct < 4; ct++) {
                #pragma unroll
                for (int i = 0; i < 4; i++) {
                    float s = sacc[ct][i] * scl;
                    if (maskt) {
                        int kv = kv0 + ct * 16 + lr;
                        int qr = q0 + lg * 4 + i;
                        if (kv > qr) s = -1e30f;
                    }
                    p[ct][i] = s;
                    rm[i] = fmaxf(rm[i], s);
                }
            }
            #pragma unroll
            for (int i = 0; i < 4; i++) {
                float v = rm[i];
                v = fmaxf(v, __shfl_xor(v, 1));
                v = fmaxf(v, __shfl_xor(v, 2));
                v = fmaxf(v, __shfl_xor(v, 4));
                v = fmaxf(v, __shfl_xor(v, 8));
                rm[i] = v;
            }
            if (t == t0) {
                // first active tile: mrow=-inf, lrow=0, oacc=0 -> direct init,
                // skip the rescale (all its products are zero).
                #pragma unroll
                for (int i = 0; i < 4; i++) mrow[i] = rm[i];
            } else {
                #pragma unroll
                for (int i = 0; i < 4; i++) {
                    float mn = fmaxf(mrow[i], rm[i]);
                    float scale = __expf(mrow[i] - mn);
                    mrow[i] = mn;
                    lrow[i] *= scale;
                    for (int d = 0; d < 4; d++) oacc[d][i] *= scale;
                }
            }
            float rs[4];
            #pragma unroll
            for (int i = 0; i < 4; i++) {
                float sum = 0.f;
                #pragma unroll
                for (int ct = 0; ct < 4; ct++) {
                    float e = __expf(p[ct][i] - mrow[i]);
                    p[ct][i] = e;
                    sum += e;
                }
                rs[i] = sum;
            }
            #pragma unroll
            for (int i = 0; i < 4; i++) {
                float v = rs[i];
                v += __shfl_xor(v, 1);
                v += __shfl_xor(v, 2);
                v += __shfl_xor(v, 4);
                v += __shfl_xor(v, 8);
                lrow[i] += v;
            }

            // P (C-layout) -> per-wave LDS bf16, XOR-swizzled
            #pragma unroll
            for (int ct = 0; ct < 4; ct++) {
                #pragma unroll
                for (int i = 0; i < 4; i++) {
                    int r = lg * 4 + i;
                    int byteoff = r * 128 + (ct * 16 + lr) * 2;
                    *(short*)(plbase + (byteoff ^ ((r & 7) << 4))) = f2bf(p[ct][i]);
                }
            }

            const char* vb = (const char*)&Vl[buf][0];
            #pragma unroll
            for (int ks = 0; ks < 2; ks++) {
                int byteoff = lr * 128 + ks * 64 + lg * 16;
                short8 pf = *(const short8*)(plbase + (byteoff ^ ((lr & 7) << 4)));
                #pragma unroll
                for (int d = 0; d < 4; d++) {
                    int col = d * 16 + lr;
                    short8 vf = *(const short8*)(vb +
                        ((col * 128 + ks * 64 + lg * 16) ^ ((col & 7) << 4)));
                    oacc[d] = __builtin_amdgcn_mfma_f32_16x16x32_bf16(pf, vf, oacc[d], 0, 0, 0);
                }
            }
        }
        __syncthreads();
        buf ^= 1;
    }

    if (J == 0) {
        // single chunk: write normalized output directly
        #pragma unroll
        for (int d = 0; d < 4; d++)
            #pragma unroll
            for (int i = 0; i < 4; i++)
                out[((size_t)b * SS + q0 + lg * 4 + i) * HDIM + d * 16 + lr]
                    = oacc[d][i] / lrow[i];
    } else {
        const int pb = (b * 16 + J) * 12 + c;
        short* op = Opart + (size_t)pb * 8192 + (size_t)(w * 16) * 64;
        #pragma unroll
        for (int d = 0; d < 4; d++)
            #pragma unroll
            for (int i = 0; i < 4; i++)
                op[(lg * 4 + i) * 64 + d * 16 + lr] = f2bf(oacc[d][i]);
        if (lr == 0) {
            float* ml = Ml + (size_t)pb * 256;
            for (int i = 0; i < 4; i++) {
                ml[w * 16 + lg * 4 + i]       = mrow[i];
                ml[128 + w * 16 + lg * 4 + i] = lrow[i];
            }
        }
    }
}

// ---------------- kernel 4: combine bf16 partials -> out (J = 1..15).
// 1D grid 240 (2 row-halves per J-tile); id%8 = batch -> producers' XCD.
__global__ __launch_bounds__(256)
void attn_comb(const short* __restrict__ Opart, const float* __restrict__ Ml,
               float* __restrict__ out) {
    const int b = (int)blockIdx.x & 7;
    const int t = (int)blockIdx.x >> 3;       // 0..29
    const int J = (t >> 1) + 1;
    const int rh = t & 1;                     // row half
    const int nc = (2 * J + 4) / 3;           // ceil((2J+2)/3), 2..11
    const int tid = threadIdx.x;
    const int r = rh * 64 + (tid >> 2);       // row 0..127
    const int cq = tid & 3;                   // col quarter (16 cols)
    const int base = (b * 16 + J) * 12;

    float m = -INFINITY;
    for (int c = 0; c < nc; c++) m = fmaxf(m, Ml[(size_t)(base + c) * 256 + r]);

    float L = 0.f;
    f32x4 acc[4];
    #pragma unroll
    for (int q = 0; q < 4; q++) acc[q] = (f32x4)0.0f;
    for (int c = 0; c < nc; c++) {
        const float* ml = Ml + (size_t)(base + c) * 256;
        float sc = __expf(ml[r] - m);
        L += ml[128 + r] * sc;
        const short* op = Opart + (size_t)(base + c) * 8192 + r * 64 + cq * 16;
        #pragma unroll
        for (int q = 0; q < 2; q++) {
            short8 s = *(const short8*)(op + q * 8);
            f32x4 lo = {bf2f(s[0]), bf2f(s[1]), bf2f(s[2]), bf2f(s[3])};
            f32x4 hi = {bf2f(s[4]), bf2f(s[5]), bf2f(s[6]), bf2f(s[7])};
            acc[q * 2]     += lo * sc;
            acc[q * 2 + 1] += hi * sc;
        }
    }
    float inv = 1.0f / L;
    float* o = out + ((size_t)b * SS + J * 128 + r) * HDIM + cq * 16;
    #pragma unroll
    for (int q = 0; q < 4; q++) {
        f32x4 v = acc[q] * inv;
        *(f32x4*)(o + q * 4) = v;
    }
}

extern "C" void kernel_launch(void* const* d_in, const int* in_sizes, int n_in,
                              void* d_out, int out_size, void* d_ws, size_t ws_size,
                              hipStream_t stream) {
    const float* X  = (const float*)d_in[0];
    const float* Wq = (const float*)d_in[1];
    const float* bq = (const float*)d_in[2];
    const float* Wk = (const float*)d_in[3];
    const float* bk = (const float*)d_in[4];
    const float* Wv = (const float*)d_in[5];
    const float* bv = (const float*)d_in[6];
    float* out = (float*)d_out;

    char* ws = (char*)d_ws;
    short* Wt = (short*)(ws);                               // 294912 B
    short* Qg = (short*)(ws + 294912);                      // 2 MB
    short* Kg = (short*)(ws + 294912 + 2097152);            // 2 MB
    short* Vt = (short*)(ws + 294912 + 2 * 2097152);        // 2 MB
    size_t opOff = 294912 + 3 * (size_t)2097152;
    short* Op = (short*)(ws + opOff);                       // 1536*8192*2 = 25.2 MB
    float* Ml = (float*)(ws + opOff + (size_t)1536 * 8192 * 2);  // 1.6 MB

    prep_w<<<36, 256, 0, stream>>>(Wq, Wk, Wv, Wt);
    proj_qkv<<<512, 512, 0, stream>>>(X, Wt, bq, bk, bv, Qg, Kg, Vt);
    attn_part<<<768, 512, 0, stream>>>(Qg, Kg, Vt, Op, Ml, out);
    attn_comb<<<240, 256, 0, stream>>>(Op, Ml, out);
}